// Round 1
// baseline (550.726 us; speedup 1.0000x reference)
//
#include <hip/hip_runtime.h>
#include <cstddef>

#define HB 64
#define HN_PER 4096
#define HN_TOOL 1000
#define HD 128
#define HT 50
#define HSCALE 50.0f

constexpr int TILE_M = 64;           // gathered rows per block
constexpr int NBLK1 = (HB * HN_TOOL) / TILE_M;  // 1000

// ---------------------------------------------------------------------------
// Dense layer: out = relu(in @ W + b), in/out are [TILE_M][128] LDS tiles.
// Thread map: 16 col-threads (8 cols each) x 16 row-threads (4 rows each).
// W rows are read from global (identical across blocks -> L1/L2 broadcast).
// ---------------------------------------------------------------------------
__device__ __forceinline__ void dense_relu_layer(
    const float (*__restrict__ in)[HD], float (*__restrict__ out)[HD],
    const float* __restrict__ W, const float* __restrict__ bias, int tid)
{
    const int tn = tid & 15, tm = tid >> 4;
    const int j0 = tn * 8, m0 = tm * 4;
    float acc[4][8];
#pragma unroll
    for (int q = 0; q < 4; ++q)
#pragma unroll
        for (int j = 0; j < 8; ++j) acc[q][j] = 0.f;

#pragma unroll 4
    for (int k = 0; k < HD; ++k) {
        float a[4];
#pragma unroll
        for (int q = 0; q < 4; ++q) a[q] = in[m0 + q][k];
        const float4 w0 = *(const float4*)(W + (size_t)k * HD + j0);
        const float4 w1 = *(const float4*)(W + (size_t)k * HD + j0 + 4);
        const float wv[8] = {w0.x, w0.y, w0.z, w0.w, w1.x, w1.y, w1.z, w1.w};
#pragma unroll
        for (int q = 0; q < 4; ++q)
#pragma unroll
            for (int j = 0; j < 8; ++j)
                acc[q][j] = fmaf(a[q], wv[j], acc[q][j]);
    }
#pragma unroll
    for (int q = 0; q < 4; ++q)
#pragma unroll
        for (int j = 0; j < 8; ++j) {
            float v = acc[q][j] + bias[j0 + j];
            out[m0 + q][j0 + j] = fmaxf(v, 0.f);
        }
}

// ---------------------------------------------------------------------------
// Kernel 1: gather rows by tool_idx, run 3-layer MLP, scatter flows into
// out2 laid out as before_svd: [B][T][N_TOOL][3]. This IS output 1 of the
// reference, and doubles as the scan kernel's input.
// ---------------------------------------------------------------------------
__global__ __launch_bounds__(256) void mlp_gather_kernel(
    const float* __restrict__ x_feat,
    const int* __restrict__ tool_idx,
    const float* __restrict__ W1, const float* __restrict__ b1,
    const float* __restrict__ W2, const float* __restrict__ b2,
    const float* __restrict__ W3, const float* __restrict__ b3,
    float* __restrict__ out2)
{
    __shared__ float bufA[TILE_M][HD];   // 32 KB
    __shared__ float bufB[TILE_M][HD];   // 32 KB
    const int tid = threadIdx.x;

    // ---- stage gathered x rows: 4 threads per row, 32 floats each ----
    {
        const int i = tid >> 2;
        const int kc = (tid & 3) * 32;
        const int r = blockIdx.x * TILE_M + i;
        const int b = r / HN_TOOL;
        const int n = r - b * HN_TOOL;
        const int p = tool_idx[b * HN_TOOL + n];
        const float4* src =
            (const float4*)(x_feat + (size_t)(b * HN_PER + p) * HD + kc);
        float4* dst = (float4*)(&bufA[i][kc]);
#pragma unroll
        for (int f = 0; f < 8; ++f) dst[f] = src[f];
    }
    __syncthreads();

    dense_relu_layer(bufA, bufB, W1, b1, tid);   // h1 in bufB
    __syncthreads();
    dense_relu_layer(bufB, bufA, W2, b2, tid);   // h2 in bufA
    __syncthreads();

    // ---- layer 3: 150 outputs (= 50 timesteps x 3), scatter to out2 ----
    {
        const int tn = tid & 15, tm = tid >> 4;
        const int m0 = tm * 4;
        const int j0 = tn * 10;                  // tn==15 -> j0==150: idle
        if (j0 < 150) {
            float acc[4][10];
#pragma unroll
            for (int q = 0; q < 4; ++q)
#pragma unroll
                for (int j = 0; j < 10; ++j) acc[q][j] = 0.f;

#pragma unroll 4
            for (int k = 0; k < HD; ++k) {
                float a[4];
#pragma unroll
                for (int q = 0; q < 4; ++q) a[q] = bufA[m0 + q][k];
                float wv[10];
#pragma unroll
                for (int jj = 0; jj < 5; ++jj) {
                    float2 w = *(const float2*)(W3 + (size_t)k * 150 + j0 + jj * 2);
                    wv[2 * jj]     = w.x;
                    wv[2 * jj + 1] = w.y;
                }
#pragma unroll
                for (int q = 0; q < 4; ++q)
#pragma unroll
                    for (int j = 0; j < 10; ++j)
                        acc[q][j] = fmaf(a[q], wv[j], acc[q][j]);
            }
#pragma unroll
            for (int q = 0; q < 4; ++q) {
                const int r = blockIdx.x * TILE_M + m0 + q;
                const int b = r / HN_TOOL;
                const int n = r - b * HN_TOOL;
                float* ob = out2 + (size_t)b * HT * HN_TOOL * 3;
#pragma unroll
                for (int jj = 0; jj < 10; ++jj) {
                    const int j = j0 + jj;       // <= 149
                    const int t = j / 3;
                    const int c = j - 3 * t;
                    ob[((size_t)t * HN_TOOL + n) * 3 + c] = acc[q][jj] + b3[j];
                }
            }
        }
    }
}

// ---------------------------------------------------------------------------
// Kernel 2: per-batch sequential Kabsch scan (T=50 steps).
// One block per batch. xyz kept in registers (<=4 pts/thread).
// R from Newton polar iteration on H (H ~ 2.5e6*I -> det>0, well-cond.).
// ---------------------------------------------------------------------------
__global__ __launch_bounds__(256) void scan_kernel(
    const float* __restrict__ pos,
    const int* __restrict__ tool_idx,
    const float* __restrict__ flows,   // [B][T][N_TOOL][3] (= out2)
    float* __restrict__ out1)          // [B][T][N_TOOL][3] flow_traj
{
    const int b = blockIdx.x;
    const int tid = threadIdx.x;
    const int lane = tid & 63, wv = tid >> 6;

    float px[4], py[4], pz[4];
    int cnt = 0;
#pragma unroll
    for (int s = 0; s < 4; ++s) {
        const int n = tid + 256 * s;
        if (n < HN_TOOL) {
            const int p = tool_idx[b * HN_TOOL + n];
            const float* pp = pos + (size_t)(b * HN_PER + p) * 3;
            px[s] = pp[0] * HSCALE;
            py[s] = pp[1] * HSCALE;
            pz[s] = pp[2] * HSCALE;
            cnt = s + 1;
        }
    }

    __shared__ float red[4][16];

    for (int t = 0; t < HT; ++t) {
        const float* ft = flows + ((size_t)(b * HT + t) * HN_TOOL) * 3;
        float fx[4], fy[4], fz[4];
        float S[15];
#pragma unroll
        for (int v = 0; v < 15; ++v) S[v] = 0.f;

        for (int s = 0; s < cnt; ++s) {
            const int n = tid + 256 * s;
            fx[s] = ft[3 * n + 0];
            fy[s] = ft[3 * n + 1];
            fz[s] = ft[3 * n + 2];
            const float x = px[s], y = py[s], z = pz[s];
            const float yx = x + fx[s], yy = y + fy[s], yz = z + fz[s];
            S[0] += x;  S[1] += y;  S[2] += z;
            S[3] += fx[s]; S[4] += fy[s]; S[5] += fz[s];
            S[6]  += x * yx; S[7]  += x * yy; S[8]  += x * yz;
            S[9]  += y * yx; S[10] += y * yy; S[11] += y * yz;
            S[12] += z * yx; S[13] += z * yy; S[14] += z * yz;
        }
        // wave reduce (64 lanes), then cross-wave via LDS
#pragma unroll
        for (int v = 0; v < 15; ++v)
#pragma unroll
            for (int o = 32; o > 0; o >>= 1)
                S[v] += __shfl_xor(S[v], o, 64);
        if (lane == 0) {
#pragma unroll
            for (int v = 0; v < 15; ++v) red[wv][v] = S[v];
        }
        __syncthreads();
        float G[15];
#pragma unroll
        for (int v = 0; v < 15; ++v)
            G[v] = red[0][v] + red[1][v] + red[2][v] + red[3][v];
        __syncthreads();   // red reused next step

        const float invN = 1.0f / HN_TOOL;
        const float mux = G[0] * invN, muy = G[1] * invN, muz = G[2] * invN;
        const float mfx = G[3] * invN, mfy = G[4] * invN, mfz = G[5] * invN;
        const float myx = mux + mfx, myy = muy + mfy, myz = muz + mfz;
        const float Nf = (float)HN_TOOL;

        float X[3][3];
        X[0][0] = G[6]  - Nf * mux * myx;
        X[0][1] = G[7]  - Nf * mux * myy;
        X[0][2] = G[8]  - Nf * mux * myz;
        X[1][0] = G[9]  - Nf * muy * myx;
        X[1][1] = G[10] - Nf * muy * myy;
        X[1][2] = G[11] - Nf * muy * myz;
        X[2][0] = G[12] - Nf * muz * myx;
        X[2][1] = G[13] - Nf * muz * myy;
        X[2][2] = G[14] - Nf * muz * myz;

        // normalize so singular values ~ 1
        const float scl = 3.0f / (X[0][0] + X[1][1] + X[2][2]);
#pragma unroll
        for (int i = 0; i < 3; ++i)
#pragma unroll
            for (int j = 0; j < 3; ++j) X[i][j] *= scl;

        // Newton polar iteration: X <- 0.5*(X + X^{-T}); X^{-T} = cof(X)/det
#pragma unroll
        for (int it = 0; it < 4; ++it) {
            float C[3][3];
            C[0][0] =  (X[1][1] * X[2][2] - X[1][2] * X[2][1]);
            C[0][1] = -(X[1][0] * X[2][2] - X[1][2] * X[2][0]);
            C[0][2] =  (X[1][0] * X[2][1] - X[1][1] * X[2][0]);
            C[1][0] = -(X[0][1] * X[2][2] - X[0][2] * X[2][1]);
            C[1][1] =  (X[0][0] * X[2][2] - X[0][2] * X[2][0]);
            C[1][2] = -(X[0][0] * X[2][1] - X[0][1] * X[2][0]);
            C[2][0] =  (X[0][1] * X[1][2] - X[0][2] * X[1][1]);
            C[2][1] = -(X[0][0] * X[1][2] - X[0][2] * X[1][0]);
            C[2][2] =  (X[0][0] * X[1][1] - X[0][1] * X[1][0]);
            const float det =
                X[0][0] * C[0][0] + X[0][1] * C[0][1] + X[0][2] * C[0][2];
            const float rdet = 0.5f / det;
#pragma unroll
            for (int i = 0; i < 3; ++i)
#pragma unroll
                for (int j = 0; j < 3; ++j)
                    X[i][j] = 0.5f * X[i][j] + C[i][j] * rdet;
        }
        // Rm = R - I
        const float Rm00 = X[0][0] - 1.f, Rm01 = X[0][1],      Rm02 = X[0][2];
        const float Rm10 = X[1][0],       Rm11 = X[1][1] - 1.f, Rm12 = X[1][2];
        const float Rm20 = X[2][0],       Rm21 = X[2][1],      Rm22 = X[2][2] - 1.f;

        float* ot = out1 + ((size_t)(b * HT + t) * HN_TOOL) * 3;
        for (int s = 0; s < cnt; ++s) {
            const int n = tid + 256 * s;
            const float xc0 = px[s] - mux, xc1 = py[s] - muy, xc2 = pz[s] - muz;
            const float dx = xc0 * Rm00 + xc1 * Rm10 + xc2 * Rm20 + mfx;
            const float dy = xc0 * Rm01 + xc1 * Rm11 + xc2 * Rm21 + mfy;
            const float dz = xc0 * Rm02 + xc1 * Rm12 + xc2 * Rm22 + mfz;
            ot[3 * n + 0] = dx;
            ot[3 * n + 1] = dy;
            ot[3 * n + 2] = dz;
            px[s] += dx; py[s] += dy; pz[s] += dz;
        }
    }
}

// ---------------------------------------------------------------------------
extern "C" void kernel_launch(void* const* d_in, const int* in_sizes, int n_in,
                              void* d_out, int out_size, void* d_ws, size_t ws_size,
                              hipStream_t stream)
{
    const float* x_feat   = (const float*)d_in[0];
    const float* pos      = (const float*)d_in[1];
    const int*   tool_idx = (const int*)d_in[2];
    const float* W1 = (const float*)d_in[3];
    const float* b1 = (const float*)d_in[4];
    const float* W2 = (const float*)d_in[5];
    const float* b2 = (const float*)d_in[6];
    const float* W3 = (const float*)d_in[7];
    const float* b3 = (const float*)d_in[8];

    float* out1 = (float*)d_out;                               // flow_traj
    float* out2 = out1 + (size_t)HB * HT * HN_TOOL * 3;        // before_svd

    mlp_gather_kernel<<<NBLK1, 256, 0, stream>>>(
        x_feat, tool_idx, W1, b1, W2, b2, W3, b3, out2);
    scan_kernel<<<HB, 256, 0, stream>>>(pos, tool_idx, out2, out1);
}

// Round 3
// 481.996 us; speedup vs baseline: 1.1426x; 1.1426x over previous
//
#include <hip/hip_runtime.h>
#include <cstddef>

#define HB 64
#define HN_PER 4096
#define HN_TOOL 1000
#define HD 128
#define HT 50
#define HSCALE 50.0f

constexpr int TILE_M = 64;
constexpr int NBLK1 = (HB * HN_TOOL) / TILE_M;  // 1000
constexpr int LPAD = 132;                       // LDS row pitch (floats): 2-way bank aliasing only (free)

// ---------------------------------------------------------------------------
// In-place dense+relu on a [64][LPAD] LDS tile. 16 col-threads x 8 cols,
// 16 row-threads x 4 rows. LDS reads are ds_read_b128 (4 k at a time).
// ---------------------------------------------------------------------------
__device__ __forceinline__ void dense_relu_inplace(
    float (*__restrict__ buf)[LPAD],
    const float* __restrict__ W, const float* __restrict__ bias, int tid)
{
    const int tn = tid & 15, tm = tid >> 4;
    const int j0 = tn * 8, m0 = tm * 4;
    float acc[4][8];
#pragma unroll
    for (int q = 0; q < 4; ++q)
#pragma unroll
        for (int j = 0; j < 8; ++j) acc[q][j] = 0.f;

    for (int k = 0; k < HD; k += 4) {
        float4 a4[4];
#pragma unroll
        for (int q = 0; q < 4; ++q)
            a4[q] = *(const float4*)&buf[m0 + q][k];
        const float* ap = (const float*)a4;
#pragma unroll
        for (int kk = 0; kk < 4; ++kk) {
            const float4 w0 = *(const float4*)(W + (size_t)(k + kk) * HD + j0);
            const float4 w1 = *(const float4*)(W + (size_t)(k + kk) * HD + j0 + 4);
            const float wv[8] = {w0.x, w0.y, w0.z, w0.w, w1.x, w1.y, w1.z, w1.w};
#pragma unroll
            for (int q = 0; q < 4; ++q) {
                const float a = ap[q * 4 + kk];
#pragma unroll
                for (int j = 0; j < 8; ++j)
                    acc[q][j] = fmaf(a, wv[j], acc[q][j]);
            }
        }
    }
    __syncthreads();   // all reads of buf done
#pragma unroll
    for (int q = 0; q < 4; ++q)
#pragma unroll
        for (int j = 0; j < 8; ++j)
            buf[m0 + q][j0 + j] = fmaxf(acc[q][j] + bias[j0 + j], 0.f);
    __syncthreads();
}

// ---------------------------------------------------------------------------
// Kernel 1: gather -> 3-layer MLP -> scatter flows into out2 ([B][T][N][3],
// which IS output 1 "before_svd" and feeds the scan).
// ---------------------------------------------------------------------------
__global__ __launch_bounds__(256, 4) void mlp_gather_kernel(
    const float* __restrict__ x_feat,
    const int* __restrict__ tool_idx,
    const float* __restrict__ W1, const float* __restrict__ b1,
    const float* __restrict__ W2, const float* __restrict__ b2,
    const float* __restrict__ W3, const float* __restrict__ b3,
    float* __restrict__ out2)
{
    __shared__ float buf[TILE_M][LPAD];   // 33,792 B -> 4 blocks/CU
    const int tid = threadIdx.x;

    // ---- stage gathered x rows: 4 threads/row, 32 floats each ----
    {
        const int i = tid >> 2;
        const int kc = (tid & 3) * 32;
        const int r = blockIdx.x * TILE_M + i;
        const int b = r / HN_TOOL;
        const int n = r - b * HN_TOOL;
        const int p = tool_idx[b * HN_TOOL + n];
        const float4* src =
            (const float4*)(x_feat + (size_t)(b * HN_PER + p) * HD + kc);
        float4* dst = (float4*)(&buf[i][kc]);
#pragma unroll
        for (int f = 0; f < 8; ++f) dst[f] = src[f];
    }
    __syncthreads();

    dense_relu_inplace(buf, W1, b1, tid);
    dense_relu_inplace(buf, W2, b2, tid);

    // ---- layer 3: 150 outputs, scatter to out2 ----
    {
        const int tn = tid & 15, tm = tid >> 4;
        const int m0 = tm * 4;
        const int j0 = tn * 10;               // tn==15 idle
        if (j0 < 150) {
            float acc[4][10];
#pragma unroll
            for (int q = 0; q < 4; ++q)
#pragma unroll
                for (int j = 0; j < 10; ++j) acc[q][j] = 0.f;

            for (int k = 0; k < HD; k += 4) {
                float4 a4[4];
#pragma unroll
                for (int q = 0; q < 4; ++q)
                    a4[q] = *(const float4*)&buf[m0 + q][k];
                const float* ap = (const float*)a4;
#pragma unroll
                for (int kk = 0; kk < 4; ++kk) {
                    float wv[10];
#pragma unroll
                    for (int jj = 0; jj < 5; ++jj) {
                        float2 w = *(const float2*)(W3 + (size_t)(k + kk) * 150 + j0 + jj * 2);
                        wv[2 * jj]     = w.x;
                        wv[2 * jj + 1] = w.y;
                    }
#pragma unroll
                    for (int q = 0; q < 4; ++q) {
                        const float a = ap[q * 4 + kk];
#pragma unroll
                        for (int j = 0; j < 10; ++j)
                            acc[q][j] = fmaf(a, wv[j], acc[q][j]);
                    }
                }
            }
#pragma unroll
            for (int q = 0; q < 4; ++q) {
                const int r = blockIdx.x * TILE_M + m0 + q;
                const int b = r / HN_TOOL;
                const int n = r - b * HN_TOOL;
                float* ob = out2 + (size_t)b * HT * HN_TOOL * 3;
#pragma unroll
                for (int jj = 0; jj < 10; ++jj) {
                    const int j = j0 + jj;
                    const int t = j / 3;
                    const int c = j - 3 * t;
                    ob[((size_t)t * HN_TOOL + n) * 3 + c] = acc[q][jj] + b3[j];
                }
            }
        }
    }
}

// ---------------------------------------------------------------------------
// Wave64 sum, result valid in EVERY lane.
// DPP row_ror:{8,4,2,1} are ROTATIONS within each 16-lane row (unlike
// row_shr, which shifts zeros in and accumulates into lane 15 only —
// that was the R2 bug). Circulant add over rotations by 8/4/2/1 leaves the
// full row sum in all 16 lanes; shfl_xor(16/32) combines the 4 rows.
// ---------------------------------------------------------------------------
__device__ __forceinline__ float wave_red_sum(float v)
{
#define DPP_ADD(ctrl)                                                          \
    v += __builtin_bit_cast(float, __builtin_amdgcn_update_dpp(                \
             0, __builtin_bit_cast(int, v), (ctrl), 0xF, 0xF, true));
    DPP_ADD(0x128)   // row_ror:8
    DPP_ADD(0x124)   // row_ror:4
    DPP_ADD(0x122)   // row_ror:2
    DPP_ADD(0x121)   // row_ror:1
#undef DPP_ADD
    v += __shfl_xor(v, 16, 64);
    v += __shfl_xor(v, 32, 64);
    return v;
}

// ---------------------------------------------------------------------------
// Kernel 2: per-batch sequential Kabsch scan. One block of 256/batch.
// Flows double-buffered in LDS (prefetch t+1 during step t). mu_x tracked
// incrementally (Sum xc = 0 => mu_x(t+1) = mu_x(t) + mean_flow(t)).
// ---------------------------------------------------------------------------
__global__ __launch_bounds__(256) void scan_kernel(
    const float* __restrict__ pos,
    const int* __restrict__ tool_idx,
    const float* __restrict__ flows,   // [B][T][N_TOOL][3]
    float* __restrict__ out1)
{
    __shared__ float fl[2][3008];      // 2 x 12,032 B
    __shared__ float red[4][12];

    const int b = blockIdx.x;
    const int tid = threadIdx.x;
    const int lane = tid & 63, wv = tid >> 6;

    // ---- positions to registers ----
    float px[4], py[4], pz[4];
    int cnt = 0;
#pragma unroll
    for (int s = 0; s < 4; ++s) {
        const int n = tid + 256 * s;
        if (n < HN_TOOL) {
            const int p = tool_idx[b * HN_TOOL + n];
            const float* pp = pos + (size_t)(b * HN_PER + p) * 3;
            px[s] = pp[0] * HSCALE;
            py[s] = pp[1] * HSCALE;
            pz[s] = pp[2] * HSCALE;
            cnt = s + 1;
        }
    }

    const float4* gfl = (const float4*)(flows + (size_t)b * HT * HN_TOOL * 3);
    // 750 float4 per timestep; threads 0..249 stage 3 each.

    // ---- preamble: stage t=0 flows; reduce initial mu_x ----
    {
        float4 p0, p1, p2;
        if (tid < 250) {
            p0 = gfl[tid];
            p1 = gfl[tid + 250];
            p2 = gfl[tid + 500];
        }
        float s0 = 0.f, s1 = 0.f, s2 = 0.f;
        for (int s = 0; s < cnt; ++s) { s0 += px[s]; s1 += py[s]; s2 += pz[s]; }
        s0 = wave_red_sum(s0); s1 = wave_red_sum(s1); s2 = wave_red_sum(s2);
        if (lane == 0) { red[wv][0] = s0; red[wv][1] = s1; red[wv][2] = s2; }
        if (tid < 250) {
            float4* d = (float4*)&fl[0][0];
            d[tid] = p0; d[tid + 250] = p1; d[tid + 500] = p2;
        }
        __syncthreads();
    }
    const float invN = 1.0f / HN_TOOL;
    float mux = (red[0][0] + red[1][0] + red[2][0] + red[3][0]) * invN;
    float muy = (red[0][1] + red[1][1] + red[2][1] + red[3][1]) * invN;
    float muz = (red[0][2] + red[1][2] + red[2][2] + red[3][2]) * invN;
    __syncthreads();

    for (int t = 0; t < HT; ++t) {
        const int cur = t & 1, nxt = cur ^ 1;

        // ---- issue prefetch of t+1 flows ----
        float4 p0, p1, p2;
        const bool pf = (t + 1 < HT) && (tid < 250);
        if (pf) {
            const float4* g = gfl + (size_t)(t + 1) * 750;
            p0 = g[tid]; p1 = g[tid + 250]; p2 = g[tid + 500];
        }

        // ---- accumulate 12 sums: Sum f (3), Sum x*(x+f)^T (9) ----
        float S[12];
#pragma unroll
        for (int v = 0; v < 12; ++v) S[v] = 0.f;
        const float* fb = &fl[cur][0];
        for (int s = 0; s < cnt; ++s) {
            const int n = tid + 256 * s;
            const float fx = fb[3 * n + 0];
            const float fy = fb[3 * n + 1];
            const float fz = fb[3 * n + 2];
            const float x = px[s], y = py[s], z = pz[s];
            const float yx = x + fx, yy = y + fy, yz = z + fz;
            S[0] += fx; S[1] += fy; S[2] += fz;
            S[3] += x * yx; S[4] += x * yy; S[5] += x * yz;
            S[6] += y * yx; S[7] += y * yy; S[8] += y * yz;
            S[9] += z * yx; S[10] += z * yy; S[11] += z * yz;
        }
#pragma unroll
        for (int v = 0; v < 12; ++v) S[v] = wave_red_sum(S[v]);
        if (lane == 0) {
#pragma unroll
            for (int v = 0; v < 12; ++v) red[wv][v] = S[v];
        }
        __syncthreads();   // B1: red ready; all fl[cur] reads done

        float G[12];
#pragma unroll
        for (int v = 0; v < 12; ++v)
            G[v] = red[0][v] + red[1][v] + red[2][v] + red[3][v];

        // ---- write prefetched flows into the other buffer ----
        if (pf) {
            float4* d = (float4*)&fl[nxt][0];
            d[tid] = p0; d[tid + 250] = p1; d[tid + 500] = p2;
        }

        // ---- solve (every thread, redundantly) ----
        const float mfx = G[0] * invN, mfy = G[1] * invN, mfz = G[2] * invN;
        const float myx = mux + mfx, myy = muy + mfy, myz = muz + mfz;
        const float Nf = (float)HN_TOOL;

        float X[3][3];
        X[0][0] = G[3]  - Nf * mux * myx;
        X[0][1] = G[4]  - Nf * mux * myy;
        X[0][2] = G[5]  - Nf * mux * myz;
        X[1][0] = G[6]  - Nf * muy * myx;
        X[1][1] = G[7]  - Nf * muy * myy;
        X[1][2] = G[8]  - Nf * muy * myz;
        X[2][0] = G[9]  - Nf * muz * myx;
        X[2][1] = G[10] - Nf * muz * myy;
        X[2][2] = G[11] - Nf * muz * myz;

        const float scl = 3.0f / (X[0][0] + X[1][1] + X[2][2]);
#pragma unroll
        for (int i = 0; i < 3; ++i)
#pragma unroll
            for (int j = 0; j < 3; ++j) X[i][j] *= scl;

#pragma unroll
        for (int it = 0; it < 3; ++it) {
            float C[3][3];
            C[0][0] =  (X[1][1] * X[2][2] - X[1][2] * X[2][1]);
            C[0][1] = -(X[1][0] * X[2][2] - X[1][2] * X[2][0]);
            C[0][2] =  (X[1][0] * X[2][1] - X[1][1] * X[2][0]);
            C[1][0] = -(X[0][1] * X[2][2] - X[0][2] * X[2][1]);
            C[1][1] =  (X[0][0] * X[2][2] - X[0][2] * X[2][0]);
            C[1][2] = -(X[0][0] * X[2][1] - X[0][1] * X[2][0]);
            C[2][0] =  (X[0][1] * X[1][2] - X[0][2] * X[1][1]);
            C[2][1] = -(X[0][0] * X[1][2] - X[0][2] * X[1][0]);
            C[2][2] =  (X[0][0] * X[1][1] - X[0][1] * X[1][0]);
            const float det =
                X[0][0] * C[0][0] + X[0][1] * C[0][1] + X[0][2] * C[0][2];
            const float rdet = 0.5f / det;
#pragma unroll
            for (int i = 0; i < 3; ++i)
#pragma unroll
                for (int j = 0; j < 3; ++j)
                    X[i][j] = 0.5f * X[i][j] + C[i][j] * rdet;
        }
        const float Rm00 = X[0][0] - 1.f, Rm01 = X[0][1],       Rm02 = X[0][2];
        const float Rm10 = X[1][0],       Rm11 = X[1][1] - 1.f, Rm12 = X[1][2];
        const float Rm20 = X[2][0],       Rm21 = X[2][1],       Rm22 = X[2][2] - 1.f;

        // ---- apply: delta = xc*(R-I) + mean_flow ----
        float* ot = out1 + ((size_t)(b * HT + t) * HN_TOOL) * 3;
        for (int s = 0; s < cnt; ++s) {
            const int n = tid + 256 * s;
            const float xc0 = px[s] - mux, xc1 = py[s] - muy, xc2 = pz[s] - muz;
            const float dx = xc0 * Rm00 + xc1 * Rm10 + xc2 * Rm20 + mfx;
            const float dy = xc0 * Rm01 + xc1 * Rm11 + xc2 * Rm21 + mfy;
            const float dz = xc0 * Rm02 + xc1 * Rm12 + xc2 * Rm22 + mfz;
            ot[3 * n + 0] = dx;
            ot[3 * n + 1] = dy;
            ot[3 * n + 2] = dz;
            px[s] += dx; py[s] += dy; pz[s] += dz;
        }
        mux += mfx; muy += mfy; muz += mfz;
        __syncthreads();   // B2: fl[nxt] staged, red consumed
    }
}

// ---------------------------------------------------------------------------
extern "C" void kernel_launch(void* const* d_in, const int* in_sizes, int n_in,
                              void* d_out, int out_size, void* d_ws, size_t ws_size,
                              hipStream_t stream)
{
    const float* x_feat   = (const float*)d_in[0];
    const float* pos      = (const float*)d_in[1];
    const int*   tool_idx = (const int*)d_in[2];
    const float* W1 = (const float*)d_in[3];
    const float* b1 = (const float*)d_in[4];
    const float* W2 = (const float*)d_in[5];
    const float* b2 = (const float*)d_in[6];
    const float* W3 = (const float*)d_in[7];
    const float* b3 = (const float*)d_in[8];

    float* out1 = (float*)d_out;                               // flow_traj
    float* out2 = out1 + (size_t)HB * HT * HN_TOOL * 3;        // before_svd

    mlp_gather_kernel<<<NBLK1, 256, 0, stream>>>(
        x_feat, tool_idx, W1, b1, W2, b2, W3, b3, out2);
    scan_kernel<<<HB, 256, 0, stream>>>(pos, tool_idx, out2, out1);
}

// Round 4
// 363.007 us; speedup vs baseline: 1.5171x; 1.3278x over previous
//
#include <hip/hip_runtime.h>
#include <cstddef>

#define HB 64
#define HN_PER 4096
#define HN_TOOL 1000
#define HD 128
#define HT 50
#define HSCALE 50.0f

typedef _Float16 f16x8 __attribute__((ext_vector_type(8)));
typedef float f32x4 __attribute__((ext_vector_type(4)));

constexpr int TILE_M = 64;
constexpr int NBLK1 = (HB * HN_TOOL) / TILE_M;  // 1000
constexpr int APITCH = 136;                     // fp16 LDS row pitch

// Swizzled fp16 weight regions in d_ws (element offsets):
// frag f=(nt*4+kc), lane L, elem j  <->  W[kc*32 + (L>>4)*8 + j][nt*16 + (L&15)]
constexpr int W1_BASE = 0;          // 32 frags * 64 lanes * 8 = 16384
constexpr int W2_BASE = 16384;      // 32 frags
constexpr int W3_BASE = 32768;      // 40 frags (150 cols padded to 160)

// ---------------------------------------------------------------------------
// Pre-kernel: convert W1/W2/W3 fp32 -> fp16 in MFMA B-fragment order.
// One thread per (frag,lane); 104 frags total -> 6656 threads.
// ---------------------------------------------------------------------------
__global__ __launch_bounds__(256) void wconv_kernel(
    const float* __restrict__ W1, const float* __restrict__ W2,
    const float* __restrict__ W3, _Float16* __restrict__ ws)
{
    const int gid = blockIdx.x * 256 + threadIdx.x;
    const int lane = gid & 63, f = gid >> 6;
    const float* W; int ncols, base, fi;
    if (f < 32)       { W = W1; ncols = 128; base = W1_BASE; fi = f; }
    else if (f < 64)  { W = W2; ncols = 128; base = W2_BASE; fi = f - 32; }
    else if (f < 104) { W = W3; ncols = 150; base = W3_BASE; fi = f - 64; }
    else return;
    const int nt = fi >> 2, kc = fi & 3;
    const int col = nt * 16 + (lane & 15);
    const int k0 = kc * 32 + (lane >> 4) * 8;
    f16x8 v;
#pragma unroll
    for (int j = 0; j < 8; ++j)
        v[j] = (col < ncols) ? (_Float16)W[(size_t)(k0 + j) * ncols + col]
                             : (_Float16)0.f;
    *(f16x8*)(ws + ((size_t)(base + (fi * 64 + lane) * 8))) = v;
}

// ---------------------------------------------------------------------------
// Kernel 1: gather -> 3-layer MLP via fp16 MFMA -> scatter into out2
// ([B][T][N][3] = output 1 "before_svd", also the scan's input).
// Each of 4 waves owns 16 rows of the 64-row tile -> no inter-layer barriers.
// ---------------------------------------------------------------------------
__global__ __launch_bounds__(256) void mlp_mfma_kernel(
    const float* __restrict__ x_feat,
    const int* __restrict__ tool_idx,
    const _Float16* __restrict__ Wsw,
    const float* __restrict__ b1, const float* __restrict__ b2,
    const float* __restrict__ b3,
    float* __restrict__ out2)
{
    __shared__ __align__(16) _Float16 hA[TILE_M][APITCH];  // 17,408 B
    const int tid = threadIdx.x;
    const int lane = tid & 63, w = tid >> 6;
    const int lm = lane & 15, quad = lane >> 4;
    const int m0 = w * 16;

    // ---- gather x rows, convert to fp16: 4 threads/row, 32 floats each ----
    {
        const int i = tid >> 2;
        const int c0 = (tid & 3) * 32;
        const int r = blockIdx.x * TILE_M + i;
        const int b = r / HN_TOOL;
        const int n = r - b * HN_TOOL;
        const int p = tool_idx[b * HN_TOOL + n];
        const float4* src =
            (const float4*)(x_feat + (size_t)(b * HN_PER + p) * HD + c0);
#pragma unroll
        for (int fq = 0; fq < 4; ++fq) {
            const float4 u = src[2 * fq], v = src[2 * fq + 1];
            f16x8 h = {(_Float16)u.x, (_Float16)u.y, (_Float16)u.z, (_Float16)u.w,
                       (_Float16)v.x, (_Float16)v.y, (_Float16)v.z, (_Float16)v.w};
            *(f16x8*)&hA[i][c0 + fq * 8] = h;
        }
    }
    __syncthreads();   // only barrier in the kernel

    // ---- layers 1 & 2: [16x128] = [16x128]@[128x128], relu, back to LDS ----
#pragma unroll
    for (int layer = 0; layer < 2; ++layer) {
        const _Float16* wb = Wsw + (layer ? W2_BASE : W1_BASE);
        const float* bias = layer ? b2 : b1;
        f16x8 afr[4];
#pragma unroll
        for (int kc = 0; kc < 4; ++kc)
            afr[kc] = *(const f16x8*)&hA[m0 + lm][kc * 32 + quad * 8];
        f32x4 acc[8];
#pragma unroll
        for (int nt = 0; nt < 8; ++nt) acc[nt] = (f32x4){0.f, 0.f, 0.f, 0.f};
#pragma unroll
        for (int kc = 0; kc < 4; ++kc)
#pragma unroll
            for (int nt = 0; nt < 8; ++nt) {
                const f16x8 bf = *(const f16x8*)(wb + (size_t)((nt * 4 + kc) * 64 + lane) * 8);
                acc[nt] = __builtin_amdgcn_mfma_f32_16x16x32_f16(afr[kc], bf, acc[nt], 0, 0, 0);
            }
        // epilogue: C/D row=quad*4+reg, col=lane&15 -> wave-private rows
#pragma unroll
        for (int nt = 0; nt < 8; ++nt) {
            const float bb = bias[nt * 16 + lm];
#pragma unroll
            for (int r = 0; r < 4; ++r)
                hA[m0 + quad * 4 + r][nt * 16 + lm] =
                    (_Float16)fmaxf(acc[nt][r] + bb, 0.f);
        }
    }

    // ---- layer 3: [16x160(150)] -> scatter to out2 ----
    {
        f16x8 afr[4];
#pragma unroll
        for (int kc = 0; kc < 4; ++kc)
            afr[kc] = *(const f16x8*)&hA[m0 + lm][kc * 32 + quad * 8];
        f32x4 acc[10];
#pragma unroll
        for (int nt = 0; nt < 10; ++nt) acc[nt] = (f32x4){0.f, 0.f, 0.f, 0.f};
#pragma unroll
        for (int kc = 0; kc < 4; ++kc)
#pragma unroll
            for (int nt = 0; nt < 10; ++nt) {
                const f16x8 bf = *(const f16x8*)(Wsw + W3_BASE + (size_t)((nt * 4 + kc) * 64 + lane) * 8);
                acc[nt] = __builtin_amdgcn_mfma_f32_16x16x32_f16(afr[kc], bf, acc[nt], 0, 0, 0);
            }
#pragma unroll
        for (int nt = 0; nt < 10; ++nt) {
            const int j = nt * 16 + lm;       // 0..159
            if (j < 150) {
                const float bb = b3[j];
                const int t = j / 3, c = j - 3 * t;
#pragma unroll
                for (int r = 0; r < 4; ++r) {
                    const int gr = blockIdx.x * TILE_M + m0 + quad * 4 + r;
                    const int b = gr / HN_TOOL;
                    const int n = gr - b * HN_TOOL;
                    out2[(size_t)b * HT * HN_TOOL * 3 +
                         ((size_t)t * HN_TOOL + n) * 3 + c] = acc[nt][r] + bb;
                }
            }
        }
    }
}

// ---------------------------------------------------------------------------
// Wave64 sum, result valid in EVERY lane (row_ror rotations + shfl_xor).
// ---------------------------------------------------------------------------
__device__ __forceinline__ float wave_red_sum(float v)
{
#define DPP_ADD(ctrl)                                                          \
    v += __builtin_bit_cast(float, __builtin_amdgcn_update_dpp(                \
             0, __builtin_bit_cast(int, v), (ctrl), 0xF, 0xF, true));
    DPP_ADD(0x128)   // row_ror:8
    DPP_ADD(0x124)   // row_ror:4
    DPP_ADD(0x122)   // row_ror:2
    DPP_ADD(0x121)   // row_ror:1
#undef DPP_ADD
    v += __shfl_xor(v, 16, 64);
    v += __shfl_xor(v, 32, 64);
    return v;
}

// LDS-only barrier: skip the vmcnt(0) drain __syncthreads would impose —
// the scattered out1 stores and flow prefetch loads stay in flight.
__device__ __forceinline__ void barrier_lgkm()
{
    asm volatile("s_waitcnt lgkmcnt(0)\n\ts_barrier" ::: "memory");
}

// ---------------------------------------------------------------------------
// Kernel 2: per-batch sequential Kabsch scan. 512 threads/block (<=2 pts/thr).
// Flows double-buffered in LDS; mu_x tracked incrementally.
// ---------------------------------------------------------------------------
__global__ __launch_bounds__(512) void scan_kernel(
    const float* __restrict__ pos,
    const int* __restrict__ tool_idx,
    const float* __restrict__ flows,   // [B][T][N_TOOL][3]
    float* __restrict__ out1)
{
    __shared__ float fl[2][3000];      // 750 float4 per buffer
    __shared__ float red[8][12];

    const int b = blockIdx.x;
    const int tid = threadIdx.x;
    const int lane = tid & 63, wv = tid >> 6;
    const int n1 = tid + 512;
    const bool has1 = n1 < HN_TOOL;

    float px[2], py[2], pz[2];
    {
        const int p = tool_idx[b * HN_TOOL + tid];
        const float* pp = pos + (size_t)(b * HN_PER + p) * 3;
        px[0] = pp[0] * HSCALE; py[0] = pp[1] * HSCALE; pz[0] = pp[2] * HSCALE;
    }
    if (has1) {
        const int p = tool_idx[b * HN_TOOL + n1];
        const float* pp = pos + (size_t)(b * HN_PER + p) * 3;
        px[1] = pp[0] * HSCALE; py[1] = pp[1] * HSCALE; pz[1] = pp[2] * HSCALE;
    }

    const float4* gfl = (const float4*)(flows + (size_t)b * HT * HN_TOOL * 3);

    // ---- preamble: stage t=0 flows; reduce initial mu_x ----
    {
        float4 p0, p1;
        if (tid < 375) { p0 = gfl[tid]; p1 = gfl[tid + 375]; }
        float s0 = px[0], s1 = py[0], s2 = pz[0];
        if (has1) { s0 += px[1]; s1 += py[1]; s2 += pz[1]; }
        s0 = wave_red_sum(s0); s1 = wave_red_sum(s1); s2 = wave_red_sum(s2);
        if (lane == 0) { red[wv][0] = s0; red[wv][1] = s1; red[wv][2] = s2; }
        if (tid < 375) {
            float4* d = (float4*)&fl[0][0];
            d[tid] = p0; d[tid + 375] = p1;
        }
        __syncthreads();
    }
    const float invN = 1.0f / HN_TOOL;
    float mux = 0.f, muy = 0.f, muz = 0.f;
#pragma unroll
    for (int w = 0; w < 8; ++w) {
        mux += red[w][0]; muy += red[w][1]; muz += red[w][2];
    }
    mux *= invN; muy *= invN; muz *= invN;
    __syncthreads();

    for (int t = 0; t < HT; ++t) {
        const int cur = t & 1, nxt = cur ^ 1;

        float4 p0, p1;
        const bool pf = (t + 1 < HT) && (tid < 375);
        if (pf) {
            const float4* g = gfl + (size_t)(t + 1) * 750;
            p0 = g[tid]; p1 = g[tid + 375];
        }

        // ---- accumulate 12 sums: Sum f (3), Sum x*(x+f)^T (9) ----
        float S[12];
        float fx0, fy0, fz0, fx1, fy1, fz1;
        {
            const float* fb = &fl[cur][0];
            fx0 = fb[3 * tid + 0]; fy0 = fb[3 * tid + 1]; fz0 = fb[3 * tid + 2];
            const float x = px[0], y = py[0], z = pz[0];
            const float yx = x + fx0, yy = y + fy0, yz = z + fz0;
            S[0] = fx0; S[1] = fy0; S[2] = fz0;
            S[3] = x * yx; S[4] = x * yy; S[5] = x * yz;
            S[6] = y * yx; S[7] = y * yy; S[8] = y * yz;
            S[9] = z * yx; S[10] = z * yy; S[11] = z * yz;
            if (has1) {
                fx1 = fb[3 * n1 + 0]; fy1 = fb[3 * n1 + 1]; fz1 = fb[3 * n1 + 2];
                const float a = px[1], c = py[1], e = pz[1];
                const float wx = a + fx1, wy = c + fy1, wz = e + fz1;
                S[0] += fx1; S[1] += fy1; S[2] += fz1;
                S[3] += a * wx; S[4] += a * wy; S[5] += a * wz;
                S[6] += c * wx; S[7] += c * wy; S[8] += c * wz;
                S[9] += e * wx; S[10] += e * wy; S[11] += e * wz;
            }
        }
#pragma unroll
        for (int v = 0; v < 12; ++v) S[v] = wave_red_sum(S[v]);
        if (lane == 0) {
#pragma unroll
            for (int v = 0; v < 12; ++v) red[wv][v] = S[v];
        }
        barrier_lgkm();   // B1

        float G[12];
#pragma unroll
        for (int v = 0; v < 12; ++v) {
            float g = 0.f;
#pragma unroll
            for (int w = 0; w < 8; ++w) g += red[w][v];
            G[v] = g;
        }

        if (pf) {
            float4* d = (float4*)&fl[nxt][0];
            d[tid] = p0; d[tid + 375] = p1;
        }

        // ---- solve (redundant per thread) ----
        const float mfx = G[0] * invN, mfy = G[1] * invN, mfz = G[2] * invN;
        const float myx = mux + mfx, myy = muy + mfy, myz = muz + mfz;
        const float Nf = (float)HN_TOOL;

        float X[3][3];
        X[0][0] = G[3]  - Nf * mux * myx;
        X[0][1] = G[4]  - Nf * mux * myy;
        X[0][2] = G[5]  - Nf * mux * myz;
        X[1][0] = G[6]  - Nf * muy * myx;
        X[1][1] = G[7]  - Nf * muy * myy;
        X[1][2] = G[8]  - Nf * muy * myz;
        X[2][0] = G[9]  - Nf * muz * myx;
        X[2][1] = G[10] - Nf * muz * myy;
        X[2][2] = G[11] - Nf * muz * myz;

        const float scl = 3.0f / (X[0][0] + X[1][1] + X[2][2]);
#pragma unroll
        for (int i = 0; i < 3; ++i)
#pragma unroll
            for (int j = 0; j < 3; ++j) X[i][j] *= scl;

#pragma unroll
        for (int it = 0; it < 2; ++it) {
            float C[3][3];
            C[0][0] =  (X[1][1] * X[2][2] - X[1][2] * X[2][1]);
            C[0][1] = -(X[1][0] * X[2][2] - X[1][2] * X[2][0]);
            C[0][2] =  (X[1][0] * X[2][1] - X[1][1] * X[2][0]);
            C[1][0] = -(X[0][1] * X[2][2] - X[0][2] * X[2][1]);
            C[1][1] =  (X[0][0] * X[2][2] - X[0][2] * X[2][0]);
            C[1][2] = -(X[0][0] * X[2][1] - X[0][1] * X[2][0]);
            C[2][0] =  (X[0][1] * X[1][2] - X[0][2] * X[1][1]);
            C[2][1] = -(X[0][0] * X[1][2] - X[0][2] * X[1][0]);
            C[2][2] =  (X[0][0] * X[1][1] - X[0][1] * X[1][0]);
            const float det =
                X[0][0] * C[0][0] + X[0][1] * C[0][1] + X[0][2] * C[0][2];
            const float rdet = 0.5f / det;
#pragma unroll
            for (int i = 0; i < 3; ++i)
#pragma unroll
                for (int j = 0; j < 3; ++j)
                    X[i][j] = 0.5f * X[i][j] + C[i][j] * rdet;
        }
        const float Rm00 = X[0][0] - 1.f, Rm01 = X[0][1],       Rm02 = X[0][2];
        const float Rm10 = X[1][0],       Rm11 = X[1][1] - 1.f, Rm12 = X[1][2];
        const float Rm20 = X[2][0],       Rm21 = X[2][1],       Rm22 = X[2][2] - 1.f;

        // ---- apply: delta = xc*(R-I) + mean_flow ----
        float* ot = out1 + ((size_t)(b * HT + t) * HN_TOOL) * 3;
        {
            const float xc0 = px[0] - mux, xc1 = py[0] - muy, xc2 = pz[0] - muz;
            const float dx = xc0 * Rm00 + xc1 * Rm10 + xc2 * Rm20 + mfx;
            const float dy = xc0 * Rm01 + xc1 * Rm11 + xc2 * Rm21 + mfy;
            const float dz = xc0 * Rm02 + xc1 * Rm12 + xc2 * Rm22 + mfz;
            ot[3 * tid + 0] = dx; ot[3 * tid + 1] = dy; ot[3 * tid + 2] = dz;
            px[0] += dx; py[0] += dy; pz[0] += dz;
        }
        if (has1) {
            const float xc0 = px[1] - mux, xc1 = py[1] - muy, xc2 = pz[1] - muz;
            const float dx = xc0 * Rm00 + xc1 * Rm10 + xc2 * Rm20 + mfx;
            const float dy = xc0 * Rm01 + xc1 * Rm11 + xc2 * Rm21 + mfy;
            const float dz = xc0 * Rm02 + xc1 * Rm12 + xc2 * Rm22 + mfz;
            ot[3 * n1 + 0] = dx; ot[3 * n1 + 1] = dy; ot[3 * n1 + 2] = dz;
            px[1] += dx; py[1] += dy; pz[1] += dz;
        }
        mux += mfx; muy += mfy; muz += mfz;
        barrier_lgkm();   // B2
    }
}

// ---------------------------------------------------------------------------
extern "C" void kernel_launch(void* const* d_in, const int* in_sizes, int n_in,
                              void* d_out, int out_size, void* d_ws, size_t ws_size,
                              hipStream_t stream)
{
    const float* x_feat   = (const float*)d_in[0];
    const float* pos      = (const float*)d_in[1];
    const int*   tool_idx = (const int*)d_in[2];
    const float* W1 = (const float*)d_in[3];
    const float* b1 = (const float*)d_in[4];
    const float* W2 = (const float*)d_in[5];
    const float* b2 = (const float*)d_in[6];
    const float* W3 = (const float*)d_in[7];
    const float* b3 = (const float*)d_in[8];

    float* out1 = (float*)d_out;                               // flow_traj
    float* out2 = out1 + (size_t)HB * HT * HN_TOOL * 3;        // before_svd
    _Float16* wsw = (_Float16*)d_ws;                           // 104 KB

    wconv_kernel<<<26, 256, 0, stream>>>(W1, W2, W3, wsw);
    mlp_mfma_kernel<<<NBLK1, 256, 0, stream>>>(
        x_feat, tool_idx, wsw, b1, b2, b3, out2);
    scan_kernel<<<HB, 512, 0, stream>>>(pos, tool_idx, out2, out1);
}

// Round 5
// 298.083 us; speedup vs baseline: 1.8476x; 1.2178x over previous
//
#include <hip/hip_runtime.h>
#include <cstddef>

#define HB 64
#define HN_PER 4096
#define HN_TOOL 1000
#define HD 128
#define HT 50
#define HSCALE 50.0f

typedef _Float16 f16x8 __attribute__((ext_vector_type(8)));
typedef float f32x4 __attribute__((ext_vector_type(4)));

constexpr int TILE_M = 64;
constexpr int NBLK1 = (HB * HN_TOOL) / TILE_M;  // 1000
constexpr int APITCH = 136;                     // fp16 LDS row pitch

// fp16 swizzled weights live in ws halves [0, 53248) = bytes [0, 106496)
constexpr int W1_BASE = 0;
constexpr int W2_BASE = 16384;
constexpr int W3_BASE = 32768;     // 40 frags -> ends at 53248 halves

// float-indexed ws regions (after the fp16 weights)
constexpr int XC0_F = 26624;                    // [B][N][3] centered scaled pos
constexpr int C0_F  = XC0_F + HB * HN_TOOL * 3; // [B][9]  Xc0^T Xc0
constexpr int BT_F  = C0_F + HB * 9;            // [B*T][12]: B (9) + sum_f (3)
constexpr int MT_F  = BT_F + HB * HT * 12;      // [B*T][12]: P_{t+1}-P_t (9) + mf (3)
// total = 296,000 floats = 1.184 MB of ws

// ---------------------------------------------------------------------------
// Pre-kernel: convert W1/W2/W3 fp32 -> fp16 in MFMA B-fragment order.
// ---------------------------------------------------------------------------
__global__ __launch_bounds__(256) void wconv_kernel(
    const float* __restrict__ W1, const float* __restrict__ W2,
    const float* __restrict__ W3, _Float16* __restrict__ ws)
{
    const int gid = blockIdx.x * 256 + threadIdx.x;
    const int lane = gid & 63, f = gid >> 6;
    const float* W; int ncols, base, fi;
    if (f < 32)       { W = W1; ncols = 128; base = W1_BASE; fi = f; }
    else if (f < 64)  { W = W2; ncols = 128; base = W2_BASE; fi = f - 32; }
    else if (f < 104) { W = W3; ncols = 150; base = W3_BASE; fi = f - 64; }
    else return;
    const int nt = fi >> 2, kc = fi & 3;
    const int col = nt * 16 + (lane & 15);
    const int k0 = kc * 32 + (lane >> 4) * 8;
    f16x8 v;
#pragma unroll
    for (int j = 0; j < 8; ++j)
        v[j] = (col < ncols) ? (_Float16)W[(size_t)(k0 + j) * ncols + col]
                             : (_Float16)0.f;
    *(f16x8*)(ws + ((size_t)(base + (fi * 64 + lane) * 8))) = v;
}

// ---------------------------------------------------------------------------
// Wave64 sum, valid in every lane (row_ror rotations + shfl_xor).
// ---------------------------------------------------------------------------
__device__ __forceinline__ float wave_red_sum(float v)
{
#define DPP_ADD(ctrl)                                                          \
    v += __builtin_bit_cast(float, __builtin_amdgcn_update_dpp(                \
             0, __builtin_bit_cast(int, v), (ctrl), 0xF, 0xF, true));
    DPP_ADD(0x128)   // row_ror:8
    DPP_ADD(0x124)   // row_ror:4
    DPP_ADD(0x122)   // row_ror:2
    DPP_ADD(0x121)   // row_ror:1
#undef DPP_ADD
    v += __shfl_xor(v, 16, 64);
    v += __shfl_xor(v, 32, 64);
    return v;
}

// ---------------------------------------------------------------------------
// init: per batch, gather+scale pos, compute mu0, store xc0 and C0=Xc0^T Xc0.
// ---------------------------------------------------------------------------
__global__ __launch_bounds__(256) void init_kernel(
    const float* __restrict__ pos,
    const int* __restrict__ tool_idx,
    float* __restrict__ ws)
{
    __shared__ float red[4][6];
    const int b = blockIdx.x;
    const int tid = threadIdx.x;
    const int lane = tid & 63, wv = tid >> 6;

    float px[4], py[4], pz[4];
    int cnt = 0;
#pragma unroll
    for (int s = 0; s < 4; ++s) {
        const int n = tid + 256 * s;
        if (n < HN_TOOL) {
            const int p = tool_idx[b * HN_TOOL + n];
            const float* pp = pos + (size_t)(b * HN_PER + p) * 3;
            px[s] = pp[0] * HSCALE;
            py[s] = pp[1] * HSCALE;
            pz[s] = pp[2] * HSCALE;
            cnt = s + 1;
        }
    }
    // mu
    float s0 = 0.f, s1 = 0.f, s2 = 0.f;
    for (int s = 0; s < cnt; ++s) { s0 += px[s]; s1 += py[s]; s2 += pz[s]; }
    s0 = wave_red_sum(s0); s1 = wave_red_sum(s1); s2 = wave_red_sum(s2);
    if (lane == 0) { red[wv][0] = s0; red[wv][1] = s1; red[wv][2] = s2; }
    __syncthreads();
    const float invN = 1.0f / HN_TOOL;
    const float mux = (red[0][0] + red[1][0] + red[2][0] + red[3][0]) * invN;
    const float muy = (red[0][1] + red[1][1] + red[2][1] + red[3][1]) * invN;
    const float muz = (red[0][2] + red[1][2] + red[2][2] + red[3][2]) * invN;
    __syncthreads();

    // xc0 store + C0 accumulate
    float xx = 0.f, xy = 0.f, xz = 0.f, yy = 0.f, yz = 0.f, zz = 0.f;
    float* xc = ws + XC0_F + (size_t)b * HN_TOOL * 3;
    for (int s = 0; s < cnt; ++s) {
        const int n = tid + 256 * s;
        const float x = px[s] - mux, y = py[s] - muy, z = pz[s] - muz;
        xc[3 * n + 0] = x; xc[3 * n + 1] = y; xc[3 * n + 2] = z;
        xx += x * x; xy += x * y; xz += x * z;
        yy += y * y; yz += y * z; zz += z * z;
    }
    float c6[6] = {xx, xy, xz, yy, yz, zz};
#pragma unroll
    for (int v = 0; v < 6; ++v) c6[v] = wave_red_sum(c6[v]);
    if (lane == 0) {
#pragma unroll
        for (int v = 0; v < 6; ++v) red[wv][v] = c6[v];
    }
    __syncthreads();
    if (tid == 0) {
        float g[6];
#pragma unroll
        for (int v = 0; v < 6; ++v)
            g[v] = red[0][v] + red[1][v] + red[2][v] + red[3][v];
        float* c0 = ws + C0_F + b * 9;
        c0[0] = g[0]; c0[1] = g[1]; c0[2] = g[2];
        c0[3] = g[1]; c0[4] = g[3]; c0[5] = g[4];
        c0[6] = g[2]; c0[7] = g[4]; c0[8] = g[5];
    }
}

// ---------------------------------------------------------------------------
// Kernel 1: gather -> 3-layer MLP via fp16 MFMA -> scatter into out2
// ([B][T][N][3] = output 1 "before_svd", also the moment kernel's input).
// ---------------------------------------------------------------------------
__global__ __launch_bounds__(256) void mlp_mfma_kernel(
    const float* __restrict__ x_feat,
    const int* __restrict__ tool_idx,
    const _Float16* __restrict__ Wsw,
    const float* __restrict__ b1, const float* __restrict__ b2,
    const float* __restrict__ b3,
    float* __restrict__ out2)
{
    __shared__ __align__(16) _Float16 hA[TILE_M][APITCH];
    const int tid = threadIdx.x;
    const int lane = tid & 63, w = tid >> 6;
    const int lm = lane & 15, quad = lane >> 4;
    const int m0 = w * 16;

    {
        const int i = tid >> 2;
        const int c0 = (tid & 3) * 32;
        const int r = blockIdx.x * TILE_M + i;
        const int b = r / HN_TOOL;
        const int n = r - b * HN_TOOL;
        const int p = tool_idx[b * HN_TOOL + n];
        const float4* src =
            (const float4*)(x_feat + (size_t)(b * HN_PER + p) * HD + c0);
#pragma unroll
        for (int fq = 0; fq < 4; ++fq) {
            const float4 u = src[2 * fq], v = src[2 * fq + 1];
            f16x8 h = {(_Float16)u.x, (_Float16)u.y, (_Float16)u.z, (_Float16)u.w,
                       (_Float16)v.x, (_Float16)v.y, (_Float16)v.z, (_Float16)v.w};
            *(f16x8*)&hA[i][c0 + fq * 8] = h;
        }
    }
    __syncthreads();

#pragma unroll
    for (int layer = 0; layer < 2; ++layer) {
        const _Float16* wb = Wsw + (layer ? W2_BASE : W1_BASE);
        const float* bias = layer ? b2 : b1;
        f16x8 afr[4];
#pragma unroll
        for (int kc = 0; kc < 4; ++kc)
            afr[kc] = *(const f16x8*)&hA[m0 + lm][kc * 32 + quad * 8];
        f32x4 acc[8];
#pragma unroll
        for (int nt = 0; nt < 8; ++nt) acc[nt] = (f32x4){0.f, 0.f, 0.f, 0.f};
#pragma unroll
        for (int kc = 0; kc < 4; ++kc)
#pragma unroll
            for (int nt = 0; nt < 8; ++nt) {
                const f16x8 bf = *(const f16x8*)(wb + (size_t)((nt * 4 + kc) * 64 + lane) * 8);
                acc[nt] = __builtin_amdgcn_mfma_f32_16x16x32_f16(afr[kc], bf, acc[nt], 0, 0, 0);
            }
#pragma unroll
        for (int nt = 0; nt < 8; ++nt) {
            const float bb = bias[nt * 16 + lm];
#pragma unroll
            for (int r = 0; r < 4; ++r)
                hA[m0 + quad * 4 + r][nt * 16 + lm] =
                    (_Float16)fmaxf(acc[nt][r] + bb, 0.f);
        }
    }

    {
        f16x8 afr[4];
#pragma unroll
        for (int kc = 0; kc < 4; ++kc)
            afr[kc] = *(const f16x8*)&hA[m0 + lm][kc * 32 + quad * 8];
        f32x4 acc[10];
#pragma unroll
        for (int nt = 0; nt < 10; ++nt) acc[nt] = (f32x4){0.f, 0.f, 0.f, 0.f};
#pragma unroll
        for (int kc = 0; kc < 4; ++kc)
#pragma unroll
            for (int nt = 0; nt < 10; ++nt) {
                const f16x8 bf = *(const f16x8*)(Wsw + W3_BASE + (size_t)((nt * 4 + kc) * 64 + lane) * 8);
                acc[nt] = __builtin_amdgcn_mfma_f32_16x16x32_f16(afr[kc], bf, acc[nt], 0, 0, 0);
            }
#pragma unroll
        for (int nt = 0; nt < 10; ++nt) {
            const int j = nt * 16 + lm;
            if (j < 150) {
                const float bb = b3[j];
                const int t = j / 3, c = j - 3 * t;
#pragma unroll
                for (int r = 0; r < 4; ++r) {
                    const int gr = blockIdx.x * TILE_M + m0 + quad * 4 + r;
                    const int b = gr / HN_TOOL;
                    const int n = gr - b * HN_TOOL;
                    out2[(size_t)b * HT * HN_TOOL * 3 +
                         ((size_t)t * HN_TOOL + n) * 3 + c] = acc[nt][r] + bb;
                }
            }
        }
    }
}

// ---------------------------------------------------------------------------
// mom: for each (b,t), B = Xc0^T F (9) and sum_f (3). Fully parallel.
// ---------------------------------------------------------------------------
__global__ __launch_bounds__(256) void mom_kernel(
    const float* __restrict__ flows,   // out2 [B][T][N][3]
    float* __restrict__ ws)
{
    __shared__ float red[4][12];
    const int t = blockIdx.x, b = blockIdx.y;
    const int tid = threadIdx.x;
    const int lane = tid & 63, wv = tid >> 6;

    const float* xc = ws + XC0_F + (size_t)b * HN_TOOL * 3;
    const float* f = flows + ((size_t)(b * HT + t) * HN_TOOL) * 3;

    float S[12];
#pragma unroll
    for (int v = 0; v < 12; ++v) S[v] = 0.f;
#pragma unroll
    for (int s = 0; s < 4; ++s) {
        const int n = tid + 256 * s;
        if (n < HN_TOOL) {
            const float x = xc[3 * n + 0], y = xc[3 * n + 1], z = xc[3 * n + 2];
            const float fx = f[3 * n + 0], fy = f[3 * n + 1], fz = f[3 * n + 2];
            S[0] += x * fx; S[1] += x * fy; S[2] += x * fz;
            S[3] += y * fx; S[4] += y * fy; S[5] += y * fz;
            S[6] += z * fx; S[7] += z * fy; S[8] += z * fz;
            S[9] += fx; S[10] += fy; S[11] += fz;
        }
    }
#pragma unroll
    for (int v = 0; v < 12; ++v) S[v] = wave_red_sum(S[v]);
    if (lane == 0) {
#pragma unroll
        for (int v = 0; v < 12; ++v) red[wv][v] = S[v];
    }
    __syncthreads();
    if (tid < 12)
        ws[BT_F + (size_t)(b * HT + t) * 12 + tid] =
            red[0][tid] + red[1][tid] + red[2][tid] + red[3][tid];
}

// ---------------------------------------------------------------------------
// compose: one lane per batch (single wave). Sequential over t:
//   H = P^T (C0 P + B); R = polar(H) by 2 Newton iters; M = P(R-I); P = P R.
// ---------------------------------------------------------------------------
__global__ __launch_bounds__(64) void compose_kernel(float* __restrict__ ws)
{
    const int b = threadIdx.x;
    float C0[9], P[9];
#pragma unroll
    for (int v = 0; v < 9; ++v) C0[v] = ws[C0_F + b * 9 + v];
    P[0] = 1.f; P[1] = 0.f; P[2] = 0.f;
    P[3] = 0.f; P[4] = 1.f; P[5] = 0.f;
    P[6] = 0.f; P[7] = 0.f; P[8] = 1.f;

    const float invN = 1.0f / HN_TOOL;
    const float* bt = ws + BT_F + (size_t)b * HT * 12;
    float* mt = ws + MT_F + (size_t)b * HT * 12;

    float4 n0 = *(const float4*)(bt);
    float4 n1 = *(const float4*)(bt + 4);
    float4 n2 = *(const float4*)(bt + 8);

    for (int t = 0; t < HT; ++t) {
        const float Bv[12] = {n0.x, n0.y, n0.z, n0.w, n1.x, n1.y, n1.z, n1.w,
                              n2.x, n2.y, n2.z, n2.w};
        if (t + 1 < HT) {
            const float* nb = bt + (t + 1) * 12;
            n0 = *(const float4*)(nb);
            n1 = *(const float4*)(nb + 4);
            n2 = *(const float4*)(nb + 8);
        }
        // G = C0*P + B
        float G[9];
#pragma unroll
        for (int i = 0; i < 3; ++i)
#pragma unroll
            for (int j = 0; j < 3; ++j)
                G[i * 3 + j] = C0[i * 3 + 0] * P[0 * 3 + j] +
                               C0[i * 3 + 1] * P[1 * 3 + j] +
                               C0[i * 3 + 2] * P[2 * 3 + j] + Bv[i * 3 + j];
        // H = P^T * G
        float X[9];
#pragma unroll
        for (int i = 0; i < 3; ++i)
#pragma unroll
            for (int j = 0; j < 3; ++j)
                X[i * 3 + j] = P[0 * 3 + i] * G[0 * 3 + j] +
                               P[1 * 3 + i] * G[1 * 3 + j] +
                               P[2 * 3 + i] * G[2 * 3 + j];
        const float scl = 3.0f / (X[0] + X[4] + X[8]);
#pragma unroll
        for (int v = 0; v < 9; ++v) X[v] *= scl;
        // 2 Newton polar iters
#pragma unroll
        for (int it = 0; it < 2; ++it) {
            float C[9];
            C[0] =  (X[4] * X[8] - X[5] * X[7]);
            C[1] = -(X[3] * X[8] - X[5] * X[6]);
            C[2] =  (X[3] * X[7] - X[4] * X[6]);
            C[3] = -(X[1] * X[8] - X[2] * X[7]);
            C[4] =  (X[0] * X[8] - X[2] * X[6]);
            C[5] = -(X[0] * X[7] - X[1] * X[6]);
            C[6] =  (X[1] * X[5] - X[2] * X[4]);
            C[7] = -(X[0] * X[5] - X[2] * X[3]);
            C[8] =  (X[0] * X[4] - X[1] * X[3]);
            const float det = X[0] * C[0] + X[1] * C[1] + X[2] * C[2];
            const float rdet = 0.5f / det;
#pragma unroll
            for (int v = 0; v < 9; ++v) X[v] = 0.5f * X[v] + C[v] * rdet;
        }
        // Pn = P * R (R = X); M = Pn - P
        float Pn[9];
#pragma unroll
        for (int i = 0; i < 3; ++i)
#pragma unroll
            for (int j = 0; j < 3; ++j)
                Pn[i * 3 + j] = P[i * 3 + 0] * X[0 * 3 + j] +
                                P[i * 3 + 1] * X[1 * 3 + j] +
                                P[i * 3 + 2] * X[2 * 3 + j];
        float4 m0, m1, m2;
        m0.x = Pn[0] - P[0]; m0.y = Pn[1] - P[1]; m0.z = Pn[2] - P[2];
        m0.w = Pn[3] - P[3]; m1.x = Pn[4] - P[4]; m1.y = Pn[5] - P[5];
        m1.z = Pn[6] - P[6]; m1.w = Pn[7] - P[7]; m2.x = Pn[8] - P[8];
        m2.y = Bv[9] * invN; m2.z = Bv[10] * invN; m2.w = Bv[11] * invN;
        float* mo = mt + t * 12;
        *(float4*)(mo) = m0;
        *(float4*)(mo + 4) = m1;
        *(float4*)(mo + 8) = m2;
#pragma unroll
        for (int v = 0; v < 9; ++v) P[v] = Pn[v];
    }
}

// ---------------------------------------------------------------------------
// apply: out1[b][t][n] = xc0[b][n] * M[b][t] + mf[b][t]. Fully parallel.
// ---------------------------------------------------------------------------
__global__ __launch_bounds__(256) void apply_kernel(
    const float* __restrict__ ws, float* __restrict__ out1)
{
    __shared__ float M[12];
    const int t = blockIdx.x, b = blockIdx.y;
    const int tid = threadIdx.x;
    if (tid < 12) M[tid] = ws[MT_F + (size_t)(b * HT + t) * 12 + tid];
    __syncthreads();

    const float* xc = ws + XC0_F + (size_t)b * HN_TOOL * 3;
    float* ot = out1 + ((size_t)(b * HT + t) * HN_TOOL) * 3;
#pragma unroll
    for (int s = 0; s < 4; ++s) {
        const int n = tid + 256 * s;
        if (n < HN_TOOL) {
            const float x = xc[3 * n + 0], y = xc[3 * n + 1], z = xc[3 * n + 2];
            ot[3 * n + 0] = x * M[0] + y * M[3] + z * M[6] + M[9];
            ot[3 * n + 1] = x * M[1] + y * M[4] + z * M[7] + M[10];
            ot[3 * n + 2] = x * M[2] + y * M[5] + z * M[8] + M[11];
        }
    }
}

// ---------------------------------------------------------------------------
extern "C" void kernel_launch(void* const* d_in, const int* in_sizes, int n_in,
                              void* d_out, int out_size, void* d_ws, size_t ws_size,
                              hipStream_t stream)
{
    const float* x_feat   = (const float*)d_in[0];
    const float* pos      = (const float*)d_in[1];
    const int*   tool_idx = (const int*)d_in[2];
    const float* W1 = (const float*)d_in[3];
    const float* b1 = (const float*)d_in[4];
    const float* W2 = (const float*)d_in[5];
    const float* b2 = (const float*)d_in[6];
    const float* W3 = (const float*)d_in[7];
    const float* b3 = (const float*)d_in[8];

    float* out1 = (float*)d_out;                               // flow_traj
    float* out2 = out1 + (size_t)HB * HT * HN_TOOL * 3;        // before_svd
    _Float16* wsw = (_Float16*)d_ws;
    float* wsf = (float*)d_ws;

    wconv_kernel<<<26, 256, 0, stream>>>(W1, W2, W3, wsw);
    init_kernel<<<HB, 256, 0, stream>>>(pos, tool_idx, wsf);
    mlp_mfma_kernel<<<NBLK1, 256, 0, stream>>>(
        x_feat, tool_idx, wsw, b1, b2, b3, out2);
    mom_kernel<<<dim3(HT, HB), 256, 0, stream>>>(out2, wsf);
    compose_kernel<<<1, 64, 0, stream>>>(wsf);
    apply_kernel<<<dim3(HT, HB), 256, 0, stream>>>(wsf, out1);
}